// Round 2
// baseline (258.072 us; speedup 1.0000x reference)
//
#include <hip/hip_runtime.h>
#include <hip/hip_bf16.h>
#include <cstdint>
#include <cstddef>

#define B_  4
#define T_  2048
#define C_  768
#define NH_ 12
#define HD_ 64

typedef __bf16 bf16_t;
typedef __attribute__((ext_vector_type(8))) __bf16 bf16x8;
typedef __attribute__((ext_vector_type(4))) __bf16 bf16x4;
typedef __attribute__((ext_vector_type(4))) float floatx4;
typedef __attribute__((ext_vector_type(8))) unsigned short ushort8;

#define MFMA16(a, b, c) __builtin_amdgcn_mfma_f32_16x16x32_bf16((a), (b), (c), 0, 0, 0)

// exp2 constants: p = exp2(s_raw * 0.125 * log2e - 12 * log2e)
#define SM_C1 0.18033688f
#define SM_C2 -17.3123405f

typedef const __attribute__((address_space(1))) uint8_t* gptr_t;
typedef __attribute__((address_space(3))) uint8_t* lptr_t;

static __device__ __forceinline__ void gld16(const void* g, void* l) {
    // per-lane global address; LDS dest = wave-uniform base + lane*16
    __builtin_amdgcn_global_load_lds((gptr_t)g, (lptr_t)l, 16, 0, 0);
}

static __device__ __forceinline__ float bfl(unsigned p) {       // low bf16 -> f32
    return __builtin_bit_cast(float, p << 16);
}
static __device__ __forceinline__ float bfh(unsigned p) {       // high bf16 -> f32
    return __builtin_bit_cast(float, p & 0xffff0000u);
}

// ---------------------------------------------------------------------------
// fp32 fallback conversion only (bf16 case: all kernels read raw inputs).
// Discriminator: cos[0][0]==1.0 -> first u16 0x3F80 if bf16, 0x0000 if fp32.
// ---------------------------------------------------------------------------
__global__ __launch_bounds__(256) void cvt_all_kernel(
    const void* s0, const void* s1, const void* s2, const void* s3,
    const void* s4, const void* s5, const void* s6, const void* s7, const void* s8,
    bf16_t* d0, bf16_t* d1, bf16_t* d2, bf16_t* d3,
    bf16_t* d4, bf16_t* d5, bf16_t* d6, bf16_t* d7, bf16_t* d8)
{
    const bool isf32 = (((const unsigned short*)s2)[0] == 0);
    if (!isf32) return;
    const void* srcs[9] = {s0, s1, s2, s3, s4, s5, s6, s7, s8};
    bf16_t*     dsts[9] = {d0, d1, d2, d3, d4, d5, d6, d7, d8};
    const int   ns[9]   = {B_*T_*C_, B_*T_*C_, T_*32, T_*32,
                           C_*C_, C_*C_, C_*C_, C_*C_, 144};
    const int t = blockIdx.y;
    const float* sf = (const float*)srcs[t];
    bf16_t*     dst = dsts[t];
    const int   nc  = ns[t] >> 3;
    const int stride = gridDim.x * 256;
    for (int i = blockIdx.x * 256 + threadIdx.x; i < nc; i += stride) {
        ushort8 o;
#pragma unroll
        for (int j = 0; j < 8; j++)
            o[j] = (unsigned short)__builtin_bit_cast(unsigned short,
                     (bf16_t)sf[i * 8 + j]);
        *(ushort8*)&dst[i * 8] = o;
    }
}

// ---------------------------------------------------------------------------
// Fused QKV GEMM + rope/rms (Q,K) + gate/ve (V) -- 256x256-tile 8-phase
// pipeline (T2 st_16x32 LDS swizzle + T3/T4 counted-vmcnt phases + T5
// setprio). Merged N: [Wq;Wk;Wv] = 2304 cols, each 256-tile inside one
// matrix. 512 threads = 8 waves (2M x 4N), per-wave 128x64 output.
// LDS 128 KiB: A[2dbuf][2half][128][64]b16 + B same. Staging via
// global_load_lds w=16 with PRE-SWIZZLED global source (byte bit9 -> bit5
// XOR within each 1KiB subtile); ds_reads apply the same XOR.
// Phase schedule per K-tile t (dbuf d = t&1), slots verified free-by-read:
//   ph1: read afA(i0-3,x2ks)+bfA(j0-1)  | stage B[d^1]h1(t+1) | bar | 16 MFMA | bar
//   ph2: read bfB(j2-3)                 | stage A[d^1]h1(t+1) | bar | 16 MFMA | bar
//   ph3: read afB(i4-7)                 | stage B[d]h0(t+2)   | bar | 16 MFMA | bar
//   ph4: (no reads)                     | stage A[d]h0(t+2)   | bar | 16 MFMA |
//        vmcnt(4) | bar      <-- counted, never 0 in-loop
// Tail: stage indices wrap mod NT (harmless garbage, drained by the
// epilogue __syncthreads before LDS reuse).
// Outputs identical to previous round: qn,kn [b][t][C] rope+rms'd; vt
// [b*12+h][d][t-perm] with the round-4-verified 64-token permutation.
// ---------------------------------------------------------------------------
__global__ __launch_bounds__(512) void gemm_qkv_fused(
    const void* xr,  const bf16_t* xc,
    const void* wqr, const bf16_t* wqc,
    const void* wkr, const bf16_t* wkc,
    const void* wvr, const bf16_t* wvc,
    const void* cr,  const bf16_t* ccv,
    const void* sr,  const bf16_t* scv,
    const void* ver, const bf16_t* vec,
    const void* wgr, const bf16_t* wgc,
    bf16_t* qn, bf16_t* kn, bf16_t* vt)
{
    __shared__ alignas(16) char sm[131072];
    const bool f32 = (((const unsigned short*)cr)[0] == 0);
    const bf16_t* X  = f32 ? xc  : (const bf16_t*)xr;
    const bf16_t* WQ = f32 ? wqc : (const bf16_t*)wqr;
    const bf16_t* WK = f32 ? wkc : (const bf16_t*)wkr;
    const bf16_t* WV = f32 ? wvc : (const bf16_t*)wvr;
    const bf16_t* CC = f32 ? ccv : (const bf16_t*)cr;
    const bf16_t* SS = f32 ? scv : (const bf16_t*)sr;
    const bf16_t* VE = f32 ? vec : (const bf16_t*)ver;
    const bf16_t* WG = f32 ? wgc : (const bf16_t*)wgr;

    const int tileN = blockIdx.y;            // 0..8 over merged N=2304
    const int sel   = tileN / 3;             // 0=Q 1=K 2=V
    const int m0    = blockIdx.x * 256;
    const int brow0 = (tileN % 3) * 256;
    const bf16_t* Bm = (sel == 0) ? WQ : (sel == 1) ? WK : WV;

    const int tid  = threadIdx.x;
    const int lane = tid & 63;
    const int wid  = tid >> 6;
    const int wr   = wid >> 2;               // 0..1  (M)
    const int wc   = wid & 3;                // 0..3  (N)
    const int m16  = lane & 15;
    const int quad = lane >> 4;
    // swizzled 16B slot within a 128B row (byte bit5 ^= row bit2):
    const int qb   = (quad * 16) ^ ((m16 & 4) ? 32 : 0);

    // staging: thread -> row tid>>3 (+64 second call), 16B col (tid&7),
    // with the inverse swizzle pre-applied to the GLOBAL column.
    const int s_r  = tid >> 3;
    const int s_ce = ((tid & 7) * 8) ^ ((tid & 32) ? 16 : 0);
    char* const wdst = sm + (size_t)(tid & ~63) * 16;   // wave-uniform base

#define STA(d, h, kt) do {                                                   \
        char* _dst = wdst + ((d) * 2 + (h)) * 16384;                         \
        const bf16_t* _g = &X[(size_t)(m0 + (h) * 128 + s_r) * C_            \
                              + (kt) * 64 + s_ce];                           \
        gld16(_g, _dst);                                                     \
        gld16(_g + (size_t)64 * C_, _dst + 8192);                            \
    } while (0)
#define STB(d, h, kt) do {                                                   \
        char* _dst = wdst + 65536 + ((d) * 2 + (h)) * 16384;                 \
        const bf16_t* _g = &Bm[(size_t)(brow0 + (h) * 128 + s_r) * C_        \
                               + (kt) * 64 + s_ce];                          \
        gld16(_g, _dst);                                                     \
        gld16(_g + (size_t)64 * C_, _dst + 8192);                            \
    } while (0)

    floatx4 acc[8][4];
#pragma unroll
    for (int i = 0; i < 8; i++)
#pragma unroll
        for (int j = 0; j < 4; j++) acc[i][j] = (floatx4){0.f, 0.f, 0.f, 0.f};

    const int NT = C_ / 64;                  // 12 K-tiles

    // prologue: tile0 all 4 halves + tile1 {B0,A0}; wait all but newest 2.
    STB(0, 0, 0); STA(0, 0, 0); STB(0, 1, 0); STA(0, 1, 0);
    STB(1, 0, 1); STA(1, 0, 1);
    asm volatile("s_waitcnt vmcnt(4)" ::: "memory");
    __builtin_amdgcn_s_barrier();

    for (int t = 0; t < NT; t++) {
        const int d   = t & 1;
        const int tp1 = (t + 1 == NT) ? 0 : t + 1;           // wrap tail
        const int tp2 = (t + 2 >= NT) ? (t + 2 - NT) : t + 2;
        const char* Ah = sm + (d * 2 + wr) * 16384;
        const char* Bh = sm + 65536 + (d * 2 + (wc >> 1)) * 16384;
        const int brow = (wc & 1) * 64;

        bf16x8 afA[4][2], bfA[2][2], bfB[2][2], afB[4][2];

        // ---- phase 1 ----
#pragma unroll
        for (int i = 0; i < 4; i++)
#pragma unroll
            for (int ks = 0; ks < 2; ks++)
                afA[i][ks] = *(const bf16x8*)(Ah + (i * 16 + m16) * 128 + ks * 64 + qb);
#pragma unroll
        for (int j = 0; j < 2; j++)
#pragma unroll
            for (int ks = 0; ks < 2; ks++)
                bfA[j][ks] = *(const bf16x8*)(Bh + (brow + j * 16 + m16) * 128 + ks * 64 + qb);
        STB(d ^ 1, 1, tp1);
        __builtin_amdgcn_s_barrier();
        __builtin_amdgcn_s_setprio(1);
#pragma unroll
        for (int i = 0; i < 4; i++)
#pragma unroll
            for (int j = 0; j < 2; j++)
#pragma unroll
                for (int ks = 0; ks < 2; ks++)
                    acc[i][j] = MFMA16(afA[i][ks], bfA[j][ks], acc[i][j]);
        __builtin_amdgcn_s_setprio(0);
        __builtin_amdgcn_s_barrier();

        // ---- phase 2 ----
#pragma unroll
        for (int j = 0; j < 2; j++)
#pragma unroll
            for (int ks = 0; ks < 2; ks++)
                bfB[j][ks] = *(const bf16x8*)(Bh + (brow + (j + 2) * 16 + m16) * 128 + ks * 64 + qb);
        STA(d ^ 1, 1, tp1);
        __builtin_amdgcn_s_barrier();
        __builtin_amdgcn_s_setprio(1);
#pragma unroll
        for (int i = 0; i < 4; i++)
#pragma unroll
            for (int j = 0; j < 2; j++)
#pragma unroll
                for (int ks = 0; ks < 2; ks++)
                    acc[i][j + 2] = MFMA16(afA[i][ks], bfB[j][ks], acc[i][j + 2]);
        __builtin_amdgcn_s_setprio(0);
        __builtin_amdgcn_s_barrier();

        // ---- phase 3 ----
#pragma unroll
        for (int i = 0; i < 4; i++)
#pragma unroll
            for (int ks = 0; ks < 2; ks++)
                afB[i][ks] = *(const bf16x8*)(Ah + ((i + 4) * 16 + m16) * 128 + ks * 64 + qb);
        STB(d, 0, tp2);
        __builtin_amdgcn_s_barrier();
        __builtin_amdgcn_s_setprio(1);
#pragma unroll
        for (int i = 0; i < 4; i++)
#pragma unroll
            for (int j = 0; j < 2; j++)
#pragma unroll
                for (int ks = 0; ks < 2; ks++)
                    acc[i + 4][j + 2] = MFMA16(afB[i][ks], bfB[j][ks], acc[i + 4][j + 2]);
        __builtin_amdgcn_s_setprio(0);
        __builtin_amdgcn_s_barrier();

        // ---- phase 4 ----
        STA(d, 0, tp2);
        __builtin_amdgcn_s_barrier();
        __builtin_amdgcn_s_setprio(1);
#pragma unroll
        for (int i = 0; i < 4; i++)
#pragma unroll
            for (int j = 0; j < 2; j++)
#pragma unroll
                for (int ks = 0; ks < 2; ks++)
                    acc[i + 4][j] = MFMA16(afB[i][ks], bfA[j][ks], acc[i + 4][j]);
        __builtin_amdgcn_s_setprio(0);
        asm volatile("s_waitcnt vmcnt(4)" ::: "memory");
        __builtin_amdgcn_s_barrier();
    }
#undef STA
#undef STB

    __syncthreads();   // full drain (also catches wrapped tail stages)

    if (sel < 2) {
        // ---- Q/K epilogue: rope + rms, store [b][t][C] ----
        unsigned* csT = (unsigned*)sm;       // [256][33] packed (cos | sin<<16)
        const int tbase = m0 & 2047;
        for (int idx = tid; idx < 256 * 32; idx += 512) {
            const int rr = idx >> 5, dd = idx & 31;
            const unsigned cv = ((const unsigned short*)CC)[(tbase + rr) * 32 + dd];
            const unsigned sv = ((const unsigned short*)SS)[(tbase + rr) * 32 + dd];
            csT[rr * 33 + dd] = cv | (sv << 16);
        }
        __syncthreads();
        bf16_t* OUT = (sel == 0) ? qn : kn;
        const int colb = brow0 + wc * 64;
#pragma unroll
        for (int i = 0; i < 8; i++) {
            float c0[4], s0[4], c1[4], s1[4];
#pragma unroll
            for (int r = 0; r < 4; r++) {
                const int rl = wr * 128 + i * 16 + quad * 4 + r;
                const unsigned p0 = csT[rl * 33 + m16];
                const unsigned p1 = csT[rl * 33 + 16 + m16];
                c0[r] = bfl(p0); s0[r] = bfh(p0);
                c1[r] = bfl(p1); s1[r] = bfh(p1);
            }
            floatx4 r0, r1, r2, r3;
            float ss[4];
#pragma unroll
            for (int r = 0; r < 4; r++) {
                r0[r] = acc[i][0][r] * c0[r] - acc[i][2][r] * s0[r];
                r1[r] = acc[i][1][r] * c1[r] - acc[i][3][r] * s1[r];
                r2[r] = acc[i][0][r] * s0[r] + acc[i][2][r] * c0[r];
                r3[r] = acc[i][1][r] * s1[r] + acc[i][3][r] * c1[r];
                ss[r] = r0[r]*r0[r] + r1[r]*r1[r] + r2[r]*r2[r] + r3[r]*r3[r];
            }
#pragma unroll
            for (int r = 0; r < 4; r++) {
#pragma unroll
                for (int off = 1; off < 16; off <<= 1)
                    ss[r] += __shfl_xor(ss[r], off, 64);
            }
#pragma unroll
            for (int r = 0; r < 4; r++) {
                const float scl = rsqrtf(ss[r] * (1.f / 64.f) + 1e-6f) * 1.2f;
                const size_t rowoff = (size_t)(m0 + wr * 128 + i * 16 + quad * 4 + r) * C_
                                      + colb + m16;
                OUT[rowoff]      = (bf16_t)(r0[r] * scl);
                OUT[rowoff + 16] = (bf16_t)(r1[r] * scl);
                OUT[rowoff + 32] = (bf16_t)(r2[r] * scl);
                OUT[rowoff + 48] = (bf16_t)(r3[r] * scl);
            }
        }
    } else {
        // ---- V epilogue: gate + ve add + direct permuted store ----
        float* gT = (float*)sm;              // [4 heads][256 rows]
        const int headb = (tileN - 6) * 4;
        for (int task = tid; task < 1024; task += 512) {
            const int hh = task >> 8, row = task & 255;
            float g = 0.f;
#pragma unroll
            for (int j2 = 0; j2 < 12; j2++)
                g += (float)X[(size_t)(m0 + row) * C_ + j2]
                   * (float)WG[(headb + hh) * 12 + j2];
            gT[hh * 256 + row] = 3.f / (1.f + __expf(-g));
        }
        __syncthreads();
        const int head = headb + wc;
        const int bb = m0 >> 11, t0 = m0 & 2047;
#pragma unroll
        for (int i = 0; i < 8; i++) {
            const floatx4 gr = *(const floatx4*)&gT[wc * 256 + wr * 128 + i * 16 + quad * 4];
            const int tslot = t0 + wr * 128 + (i >> 2) * 64
                              + ((i >> 1) & 1) * 32 + quad * 8 + (i & 1) * 4;
#pragma unroll
            for (int j = 0; j < 4; j++) {
                bf16x4 o;
#pragma unroll
                for (int r = 0; r < 4; r++) {
                    const float vef = (float)VE[(size_t)(m0 + wr * 128 + i * 16 + quad * 4 + r) * C_
                                                + head * 64 + j * 16 + m16];
                    o[r] = (bf16_t)(acc[i][j][r] + gr[r] * vef);
                }
                *(bf16x4*)&vt[((size_t)(bb * NH_ + head) * HD_ + j * 16 + m16) * T_
                              + tslot] = o;
            }
        }
    }
}

// ---------------------------------------------------------------------------
// Plain GEMM for the output projection (round-4-proven).
// ---------------------------------------------------------------------------
template <bool OUT_BF16>
__device__ __forceinline__ void gemm_bt_tile(
    const bf16_t* __restrict__ A, const bf16_t* __restrict__ Bm,
    void* __restrict__ Cout, int m0, int n0, int K, int ldc)
{
    __shared__ bf16_t As[2][128 * 32];
    __shared__ bf16_t Bs[2][128 * 32];
    const int tid  = threadIdx.x;
    const int lane = tid & 63;
    const int wid  = tid >> 6;
    const int m16  = lane & 15;
    const int quad = lane >> 4;
    const int wm   = (wid >> 1) * 64;
    const int wn   = (wid & 1) * 64;
    const int srow = lane >> 2;
    const int soct = (lane & 3) * 8;

    floatx4 acc[4][4];
#pragma unroll
    for (int i = 0; i < 4; i++)
#pragma unroll
        for (int j = 0; j < 4; j++) acc[i][j] = (floatx4){0.f, 0.f, 0.f, 0.f};

    for (int k0 = 0; k0 < K; k0 += 64) {
        const bf16_t* ga0 = &A[(size_t)(m0 + 16 * wid + srow) * K + k0 + soct];
        const bf16_t* gb0 = &Bm[(size_t)(n0 + 16 * wid + srow) * K + k0 + soct];
        gld16(ga0,                       (bf16_t*)As[0] + wid * 512);
        gld16(ga0 + (size_t)64 * K,      (bf16_t*)As[0] + wid * 512 + 2048);
        gld16(gb0,                       (bf16_t*)Bs[0] + wid * 512);
        gld16(gb0 + (size_t)64 * K,      (bf16_t*)Bs[0] + wid * 512 + 2048);
        gld16(ga0 + 32,                  (bf16_t*)As[1] + wid * 512);
        gld16(ga0 + (size_t)64 * K + 32, (bf16_t*)As[1] + wid * 512 + 2048);
        gld16(gb0 + 32,                  (bf16_t*)Bs[1] + wid * 512);
        gld16(gb0 + (size_t)64 * K + 32, (bf16_t*)Bs[1] + wid * 512 + 2048);
        __syncthreads();
#pragma unroll
        for (int half = 0; half < 2; half++) {
            bf16x8 af[4], bfr[4];
#pragma unroll
            for (int i = 0; i < 4; i++)
                af[i] = *(const bf16x8*)&As[half][(wm + i * 16 + m16) * 32 + quad * 8];
#pragma unroll
            for (int j = 0; j < 4; j++)
                bfr[j] = *(const bf16x8*)&Bs[half][(wn + j * 16 + m16) * 32 + quad * 8];
#pragma unroll
            for (int i = 0; i < 4; i++)
#pragma unroll
                for (int j = 0; j < 4; j++)
                    acc[i][j] = MFMA16(af[i], bfr[j], acc[i][j]);
        }
        __syncthreads();
    }
#pragma unroll
    for (int i = 0; i < 4; i++) {
#pragma unroll
        for (int j = 0; j < 4; j++) {
            const int colg = n0 + wn + j * 16 + m16;
#pragma unroll
            for (int r = 0; r < 4; r++) {
                const int rowg = m0 + wm + i * 16 + quad * 4 + r;
                if (OUT_BF16)
                    ((bf16_t*)Cout)[(size_t)rowg * ldc + colg] = (bf16_t)acc[i][j][r];
                else
                    ((float*)Cout)[(size_t)rowg * ldc + colg] = acc[i][j][r];
            }
        }
    }
}

__global__ __launch_bounds__(256) void gemm_proj_kernel(
    const bf16_t* __restrict__ yb, const void* wpr, const bf16_t* wpc,
    void* __restrict__ out, const void* cr)
{
    const bool f32 = (((const unsigned short*)cr)[0] == 0);
    const bf16_t* WP = f32 ? wpc : (const bf16_t*)wpr;
    if (f32)
        gemm_bt_tile<false>(yb, WP, out, blockIdx.x * 128, blockIdx.y * 128, C_, C_);
    else
        gemm_bt_tile<true>(yb, WP, out, blockIdx.x * 128, blockIdx.y * 128, C_, C_);
}

// ---------------------------------------------------------------------------
// Flash attention (round-4-proven kernel; Q/K row stride C_).
// ---------------------------------------------------------------------------
__global__ __launch_bounds__(256, 3) void attn_kernel(
    const bf16_t* __restrict__ Q, const bf16_t* __restrict__ Km,
    const bf16_t* __restrict__ Vtg, bf16_t* __restrict__ Y,
    const int* __restrict__ wl)
{
    const int bx   = blockIdx.x;
    const int bh   = blockIdx.y;
    const int gsel = bh >> 4;
    int qblk;
    if (gsel == 0)      qblk = bx;
    else if (gsel == 1) qblk = 15 - bx;
    else                qblk = (int)((0xECA8642013579BDFull >> (bx * 4)) & 0xF);
    const int q0 = qblk * 128;
    const int b  = bh / NH_;
    const int h  = bh % NH_;
    const int window = wl[0];
    const int tid  = threadIdx.x;
    const int wid  = tid >> 6;
    const int lane = tid & 63;
    const int m16  = lane & 15;
    const int quad = lane >> 4;
    const int qw   = q0 + wid * 32;

    const bf16_t* Qb = Q + (size_t)b * T_ * C_ + h * HD_;   // row stride C_
    const bf16_t* Kb = Km + (size_t)b * T_ * C_ + h * HD_;
    const bf16_t* Vb = Vtg + (size_t)bh * HD_ * T_;         // [d][t-perm]

    __shared__ bf16_t Ks[2][64 * 64];
    __shared__ bf16_t Vs[2][64 * 64];

    bf16x8 qf[2][2];
#pragma unroll
    for (int mt = 0; mt < 2; mt++)
#pragma unroll
        for (int ks = 0; ks < 2; ks++)
            qf[mt][ks] = *(const bf16x8*)
                &Qb[(size_t)(qw + mt * 16 + m16) * C_ + ks * 32 + quad * 8];

    // staging: thread -> (row = tid>>2, two octets), XOR-swizzled columns
    const int srow = tid >> 2;
    const int soct = tid & 3;
    const int g0   = 2 * soct, g1 = 2 * soct + 1;
    const int kd0  = srow * 64 + ((g0 ^ (srow & 7)) << 3);
    const int kd1  = srow * 64 + ((g1 ^ (srow & 7)) << 3);
    int rsw[2];
#pragma unroll
    for (int ks = 0; ks < 2; ks++)
        rsw[ks] = (((ks * 4 + quad) ^ (m16 & 7)) << 3);

    int lo = q0 - window;
    if (lo < 0) lo = 0;
    lo &= ~63;
    const int nch = (q0 + 128 - lo) >> 6;

    floatx4 accO[2][4];
#pragma unroll
    for (int mt = 0; mt < 2; mt++)
#pragma unroll
        for (int dt = 0; dt < 4; dt++) accO[mt][dt] = (floatx4){0.f, 0.f, 0.f, 0.f};
    float lsum[2] = {0.f, 0.f};
    const bf16x4 zero4 = {(bf16_t)0.f, (bf16_t)0.f, (bf16_t)0.f, (bf16_t)0.f};

    // preload + stage chunk 0
    bf16x8 ka0 = *(const bf16x8*)&Kb[(size_t)(lo + srow) * C_ + g0 * 8];
    bf16x8 ka1 = *(const bf16x8*)&Kb[(size_t)(lo + srow) * C_ + g1 * 8];
    bf16x8 va0 = *(const bf16x8*)&Vb[(size_t)srow * T_ + lo + g0 * 8];
    bf16x8 va1 = *(const bf16x8*)&Vb[(size_t)srow * T_ + lo + g1 * 8];
    *(bf16x8*)&Ks[0][kd0] = ka0;
    *(bf16x8*)&Ks[0][kd1] = ka1;
    *(bf16x8*)&Vs[0][kd0] = va0;
    *(bf16x8*)&Vs[0][kd1] = va1;

    for (int ic = 0; ic < nch; ic++) {
        const int kc = lo + ic * 64;
        const bool more = (ic + 1 < nch);
        if (more) {
            const int kn2 = kc + 64;
            ka0 = *(const bf16x8*)&Kb[(size_t)(kn2 + srow) * C_ + g0 * 8];
            ka1 = *(const bf16x8*)&Kb[(size_t)(kn2 + srow) * C_ + g1 * 8];
            va0 = *(const bf16x8*)&Vb[(size_t)srow * T_ + kn2 + g0 * 8];
            va1 = *(const bf16x8*)&Vb[(size_t)srow * T_ + kn2 + g1 * 8];
        }
        __syncthreads();
        const int buf = ic & 1;

        const bool skip = (kc > qw + 31) || (kc + 63 < qw - window);
        if (!skip) {
            bf16x8 kf[4][2];
#pragma unroll
            for (int nt = 0; nt < 4; nt++) {
                const int rb = (nt * 16 + m16) * 64;
                kf[nt][0] = *(const bf16x8*)&Ks[buf][rb + rsw[0]];
                kf[nt][1] = *(const bf16x8*)&Ks[buf][rb + rsw[1]];
            }
            bf16x4 pk[2][4];
            unsigned livemask = 0;
#pragma unroll
            for (int mt = 0; mt < 2; mt++) {
                const int qmin = qw + mt * 16, qmax = qmin + 15;
                float lacc = 0.f;
#pragma unroll
                for (int nt = 0; nt < 4; nt++) {
                    const int kmin = kc + nt * 16, kmax = kmin + 15;
                    if (kmin > qmax || kmax < qmin - window) {
                        pk[mt][nt] = zero4;
                        continue;
                    }
                    livemask |= 1u << (mt * 4 + nt);
                    floatx4 z = (floatx4){0.f, 0.f, 0.f, 0.f};
                    z = MFMA16(kf[nt][0], qf[mt][0], z);
                    z = MFMA16(kf[nt][1], qf[mt][1], z);
                    const bool edge = (kmax > qmin) || (kmin < qmax - window);
                    const int query = qmin + m16;
                    bf16x4 t4;
#pragma unroll
                    for (int r = 0; r < 4; r++) {
                        float p = __builtin_amdgcn_exp2f(
                            fmaf(z[r], SM_C1, SM_C2));
                        if (edge) {
                            const int key = kmin + quad * 4 + r;
                            const bool ok = (key <= query) &&
                                            (query - key <= window);
                            p = ok ? p : 0.f;
                        }
                        t4[r] = (bf16_t)p;
                        lacc += p;
                    }
                    pk[mt][nt] = t4;
                }
                lsum[mt] += lacc;
            }
#pragma unroll
            for (int pr = 0; pr < 2; pr++) {
                const unsigned pm0 = (livemask >> (2 * pr)) & 3u;
                const unsigned pm1 = (livemask >> (4 + 2 * pr)) & 3u;
                if (!(pm0 | pm1)) continue;
                const bf16x8 pa0 = __builtin_shufflevector(
                    pk[0][2 * pr], pk[0][2 * pr + 1], 0, 1, 2, 3, 4, 5, 6, 7);
                const bf16x8 pa1 = __builtin_shufflevector(
                    pk[1][2 * pr], pk[1][2 * pr + 1], 0, 1, 2, 3, 4, 5, 6, 7);
                const int vco = (((pr * 4 + quad) ^ (m16 & 7)) << 3);
#pragma unroll
                for (int dt = 0; dt < 4; dt++) {
                    const bf16x8 vf = *(const bf16x8*)
                        &Vs[buf][(dt * 16 + m16) * 64 + vco];
                    if (pm0) accO[0][dt] = MFMA16(pa0, vf, accO[0][dt]);
                    if (pm1) accO[1][dt] = MFMA16(pa1, vf, accO[1][dt]);
                }
            }
        }

        if (more) {
            const int nb = buf ^ 1;
            *(bf16x8*)&Ks[nb][kd0] = ka0;
            *(bf16x8*)&Ks[nb][kd1] = ka1;
            *(bf16x8*)&Vs[nb][kd0] = va0;
            *(bf16x8*)&Vs[nb][kd1] = va1;
        }
    }

#pragma unroll
    for (int mt = 0; mt < 2; mt++) {
        float red = lsum[mt];
        red += __shfl_xor(red, 16, 64);
        red += __shfl_xor(red, 32, 64);
#pragma unroll
        for (int r = 0; r < 4; r++) {
            const float lq  = __shfl(red, quad * 4 + r, 64);
            const float inv = 1.f / lq;
            const int   tq  = qw + mt * 16 + quad * 4 + r;
#pragma unroll
            for (int dt = 0; dt < 4; dt++)
                Y[((size_t)b * T_ + tq) * C_ + h * HD_ + dt * 16 + m16] =
                    (bf16_t)(accO[mt][dt][r] * inv);
        }
    }
}

// ---------------------------------------------------------------------------
extern "C" void kernel_launch(void* const* d_in, const int* in_sizes, int n_in,
                              void* d_out, int out_size, void* d_ws, size_t ws_size,
                              hipStream_t stream)
{
    const void* x_raw   = d_in[0];
    const void* ve_raw  = d_in[1];
    const void* cos_raw = d_in[2];
    const void* sin_raw = d_in[3];
    const void* wq_raw  = d_in[4];
    const void* wk_raw  = d_in[5];
    const void* wv_raw  = d_in[6];
    const void* wp_raw  = d_in[7];
    const void* wg_raw  = d_in[8];
    const int*  wl      = (const int*)d_in[9];

    const size_t NTC = (size_t)B_ * T_ * C_;  // 6291456
    const size_t WSZ = (size_t)C_ * C_;       // 589824

    bf16_t* ws  = (bf16_t*)d_ws;
    bf16_t* xb  = ws;                 // NTC   (fp32-cvt targets)
    bf16_t* veb = xb + NTC;           // NTC
    bf16_t* cb  = veb + NTC;          // 65536
    bf16_t* sb  = cb + T_ * 32;       // 65536
    bf16_t* wqb = sb + T_ * 32;       // WSZ x4
    bf16_t* wkb = wqb + WSZ;
    bf16_t* wvb = wkb + WSZ;
    bf16_t* wpb = wvb + WSZ;
    bf16_t* wgb = wpb + WSZ;          // 144 (pad 256)
    bf16_t* qn  = wgb + 256;          // NTC  rope+rms Q  [b][t][C]
    bf16_t* kn  = qn + NTC;           // NTC  rope+rms K  [b][t][C]
    bf16_t* vt  = kn + NTC;           // NTC  V^T [bh][d][t-perm]
    bf16_t* yb  = vt + NTC;           // NTC  attention out [b][t][C]

    cvt_all_kernel<<<dim3(128, 9), 256, 0, stream>>>(
        x_raw, ve_raw, cos_raw, sin_raw, wq_raw, wk_raw, wv_raw, wp_raw, wg_raw,
        xb, veb, cb, sb, wqb, wkb, wvb, wpb, wgb);

    gemm_qkv_fused<<<dim3(32, 9), 512, 0, stream>>>(
        x_raw, xb, wq_raw, wqb, wk_raw, wkb, wv_raw, wvb,
        cos_raw, cb, sin_raw, sb, ve_raw, veb, wg_raw, wgb,
        qn, kn, vt);

    attn_kernel<<<dim3(16, 48), 256, 0, stream>>>(qn, kn, vt, yb, wl);

    gemm_proj_kernel<<<dim3(64, 6), 256, 0, stream>>>(yb, wp_raw, wpb, d_out, cos_raw);
}

// Round 3
// 234.603 us; speedup vs baseline: 1.1000x; 1.1000x over previous
//
#include <hip/hip_runtime.h>
#include <hip/hip_bf16.h>
#include <cstdint>
#include <cstddef>

#define B_  4
#define T_  2048
#define C_  768
#define NH_ 12
#define HD_ 64

typedef __bf16 bf16_t;
typedef __attribute__((ext_vector_type(8))) __bf16 bf16x8;
typedef __attribute__((ext_vector_type(4))) __bf16 bf16x4;
typedef __attribute__((ext_vector_type(4))) float floatx4;
typedef __attribute__((ext_vector_type(8))) unsigned short ushort8;

#define MFMA16(a, b, c) __builtin_amdgcn_mfma_f32_16x16x32_bf16((a), (b), (c), 0, 0, 0)

// exp2 constants: p = exp2(s_raw * 0.125 * log2e - 12 * log2e)
#define SM_C1 0.18033688f
#define SM_C2 -17.3123405f

typedef const __attribute__((address_space(1))) uint8_t* gptr_t;
typedef __attribute__((address_space(3))) uint8_t* lptr_t;

static __device__ __forceinline__ void gld16(const void* g, void* l) {
    // per-lane global address; LDS dest = wave-uniform base + lane*16
    __builtin_amdgcn_global_load_lds((gptr_t)g, (lptr_t)l, 16, 0, 0);
}

static __device__ __forceinline__ float bfl(unsigned p) {       // low bf16 -> f32
    return __builtin_bit_cast(float, p << 16);
}
static __device__ __forceinline__ float bfh(unsigned p) {       // high bf16 -> f32
    return __builtin_bit_cast(float, p & 0xffff0000u);
}

// ---------------------------------------------------------------------------
// fp32 fallback conversion only (bf16 case: all kernels read raw inputs).
// Discriminator: cos[0][0]==1.0 -> first u16 0x3F80 if bf16, 0x0000 if fp32.
// ---------------------------------------------------------------------------
__global__ __launch_bounds__(256) void cvt_all_kernel(
    const void* s0, const void* s1, const void* s2, const void* s3,
    const void* s4, const void* s5, const void* s6, const void* s7, const void* s8,
    bf16_t* d0, bf16_t* d1, bf16_t* d2, bf16_t* d3,
    bf16_t* d4, bf16_t* d5, bf16_t* d6, bf16_t* d7, bf16_t* d8)
{
    const bool isf32 = (((const unsigned short*)s2)[0] == 0);
    if (!isf32) return;
    const void* srcs[9] = {s0, s1, s2, s3, s4, s5, s6, s7, s8};
    bf16_t*     dsts[9] = {d0, d1, d2, d3, d4, d5, d6, d7, d8};
    const int   ns[9]   = {B_*T_*C_, B_*T_*C_, T_*32, T_*32,
                           C_*C_, C_*C_, C_*C_, C_*C_, 144};
    const int t = blockIdx.y;
    const float* sf = (const float*)srcs[t];
    bf16_t*     dst = dsts[t];
    const int   nc  = ns[t] >> 3;
    const int stride = gridDim.x * 256;
    for (int i = blockIdx.x * 256 + threadIdx.x; i < nc; i += stride) {
        ushort8 o;
#pragma unroll
        for (int j = 0; j < 8; j++)
            o[j] = (unsigned short)__builtin_bit_cast(unsigned short,
                     (bf16_t)sf[i * 8 + j]);
        *(ushort8*)&dst[i * 8] = o;
    }
}

// ---------------------------------------------------------------------------
// Fused QKV GEMM + rope/rms (Q,K) + gate/ve (V).
// 128x128 tile, BK=64, proven m97 staging. __launch_bounds__(256,3) to get
// 3 waves/SIMD (12 waves/CU = 3 blocks) -- round-2 diagnosis: reg-capped at
// 2 waves/SIMD (116 VGPR + 64 acc AGPR = 180), latency-bound.
// ---------------------------------------------------------------------------
__global__ __launch_bounds__(256, 3) void gemm_qkv_fused(
    const void* xr,  const bf16_t* xc,
    const void* wqr, const bf16_t* wqc,
    const void* wkr, const bf16_t* wkc,
    const void* wvr, const bf16_t* wvc,
    const void* cr,  const bf16_t* ccv,
    const void* sr,  const bf16_t* scv,
    const void* ver, const bf16_t* vec,
    const void* wgr, const bf16_t* wgc,
    bf16_t* qn, bf16_t* kn, bf16_t* vt)
{
    __shared__ alignas(16) char sm[36864];
    const bool f32 = (((const unsigned short*)cr)[0] == 0);
    const bf16_t* X  = f32 ? xc  : (const bf16_t*)xr;
    const bf16_t* WQ = f32 ? wqc : (const bf16_t*)wqr;
    const bf16_t* WK = f32 ? wkc : (const bf16_t*)wkr;
    const bf16_t* WV = f32 ? wvc : (const bf16_t*)wvr;
    const bf16_t* CC = f32 ? ccv : (const bf16_t*)cr;
    const bf16_t* SS = f32 ? scv : (const bf16_t*)sr;
    const bf16_t* VE = f32 ? vec : (const bf16_t*)ver;
    const bf16_t* WG = f32 ? wgc : (const bf16_t*)wgr;

    const int sel = blockIdx.y / 6;          // 0=Q 1=K 2=V
    const int nt  = blockIdx.y % 6;
    const int m0  = blockIdx.x * 128;
    const int n0  = nt * 128;
    const bf16_t* Bm = (sel == 0) ? WQ : (sel == 1) ? WK : WV;

    bf16_t* As = (bf16_t*)sm;                // 2 halves of [128][32]
    bf16_t* Bs = (bf16_t*)(sm + 16384);

    const int tid  = threadIdx.x;
    const int lane = tid & 63;
    const int wid  = tid >> 6;
    const int m16  = lane & 15;
    const int quad = lane >> 4;
    const int wm   = (wid >> 1) * 64;
    const int wn   = (wid & 1) * 64;
    const int srow = lane >> 2;
    const int soct = (lane & 3) * 8;

    floatx4 acc[4][4];
#pragma unroll
    for (int i = 0; i < 4; i++)
#pragma unroll
        for (int j = 0; j < 4; j++) acc[i][j] = (floatx4){0.f, 0.f, 0.f, 0.f};

    for (int k0 = 0; k0 < C_; k0 += 64) {
        const bf16_t* ga0 = &X[(size_t)(m0 + 16 * wid + srow) * C_ + k0 + soct];
        const bf16_t* gb0 = &Bm[(size_t)(n0 + 16 * wid + srow) * C_ + k0 + soct];
        gld16(ga0,                        As + wid * 512);
        gld16(ga0 + (size_t)64 * C_,      As + wid * 512 + 2048);
        gld16(gb0,                        Bs + wid * 512);
        gld16(gb0 + (size_t)64 * C_,      Bs + wid * 512 + 2048);
        gld16(ga0 + 32,                   As + 4096 + wid * 512);
        gld16(ga0 + (size_t)64 * C_ + 32, As + 4096 + wid * 512 + 2048);
        gld16(gb0 + 32,                   Bs + 4096 + wid * 512);
        gld16(gb0 + (size_t)64 * C_ + 32, Bs + 4096 + wid * 512 + 2048);
        __syncthreads();
#pragma unroll
        for (int half = 0; half < 2; half++) {
            bf16x8 af[4], bfr[4];
#pragma unroll
            for (int i = 0; i < 4; i++)
                af[i] = *(const bf16x8*)&As[half * 4096 + (wm + i * 16 + m16) * 32 + quad * 8];
#pragma unroll
            for (int j = 0; j < 4; j++)
                bfr[j] = *(const bf16x8*)&Bs[half * 4096 + (wn + j * 16 + m16) * 32 + quad * 8];
#pragma unroll
            for (int i = 0; i < 4; i++)
#pragma unroll
                for (int j = 0; j < 4; j++)
                    acc[i][j] = MFMA16(af[i], bfr[j], acc[i][j]);
        }
        __syncthreads();
    }

    if (sel < 2) {
        // ---- Q/K epilogue: rope + rms, store [b][t][C] ----
        unsigned* csT = (unsigned*)sm;       // [128][33] packed (cos | sin<<16)
        const int tbase = m0 & 2047;
        for (int idx = tid; idx < 128 * 32; idx += 256) {
            const int rr = idx >> 5, dd = idx & 31;
            const unsigned cv = ((const unsigned short*)CC)[(tbase + rr) * 32 + dd];
            const unsigned sv = ((const unsigned short*)SS)[(tbase + rr) * 32 + dd];
            csT[rr * 33 + dd] = cv | (sv << 16);
        }
        __syncthreads();
        bf16_t* OUT = (sel == 0) ? qn : kn;
#pragma unroll
        for (int i = 0; i < 4; i++) {
            float c0[4], s0[4], c1[4], s1[4];
#pragma unroll
            for (int r = 0; r < 4; r++) {
                const int rl = wm + i * 16 + quad * 4 + r;
                const unsigned p0 = csT[rl * 33 + m16];
                const unsigned p1 = csT[rl * 33 + 16 + m16];
                c0[r] = bfl(p0); s0[r] = bfh(p0);
                c1[r] = bfl(p1); s1[r] = bfh(p1);
            }
            floatx4 r0, r1, r2, r3;
            float ss[4];
#pragma unroll
            for (int r = 0; r < 4; r++) {
                r0[r] = acc[i][0][r] * c0[r] - acc[i][2][r] * s0[r];
                r1[r] = acc[i][1][r] * c1[r] - acc[i][3][r] * s1[r];
                r2[r] = acc[i][0][r] * s0[r] + acc[i][2][r] * c0[r];
                r3[r] = acc[i][1][r] * s1[r] + acc[i][3][r] * c1[r];
                ss[r] = r0[r]*r0[r] + r1[r]*r1[r] + r2[r]*r2[r] + r3[r]*r3[r];
            }
#pragma unroll
            for (int r = 0; r < 4; r++) {
#pragma unroll
                for (int off = 1; off < 16; off <<= 1)
                    ss[r] += __shfl_xor(ss[r], off, 64);
            }
#pragma unroll
            for (int r = 0; r < 4; r++) {
                const float scl = rsqrtf(ss[r] * (1.f / 64.f) + 1e-6f) * 1.2f;
                const size_t rowoff = (size_t)(m0 + wm + i * 16 + quad * 4 + r) * C_
                                      + n0 + wn + m16;
                OUT[rowoff]      = (bf16_t)(r0[r] * scl);
                OUT[rowoff + 16] = (bf16_t)(r1[r] * scl);
                OUT[rowoff + 32] = (bf16_t)(r2[r] * scl);
                OUT[rowoff + 48] = (bf16_t)(r3[r] * scl);
            }
        }
    } else {
        // ---- V epilogue: gate + ve add + direct permuted store ----
        bf16_t* veT = (bf16_t*)sm;             // [128 tok][136]
        float*  gT  = (float*)(sm + 34816);    // [2][128]
        for (int idx = tid; idx < 2048; idx += 256) {
            const int rr = idx >> 4, ch = idx & 15;
            *(bf16x8*)&veT[rr * 136 + ch * 8] =
                *(const bf16x8*)&VE[(size_t)(m0 + rr) * C_ + n0 + ch * 8];
        }
        {
            const int row = tid & 127, hh = tid >> 7;
            const int head = nt * 2 + hh;
            float g = 0.f;
#pragma unroll
            for (int j2 = 0; j2 < 12; j2++)
                g += (float)X[(size_t)(m0 + row) * C_ + j2] * (float)WG[head * 12 + j2];
            gT[hh * 128 + row] = 3.f / (1.f + __expf(-g));
        }
        __syncthreads();
        const int hh2  = wn >> 6;
        const int head = nt * 2 + hh2;
        const int bb = m0 >> 11, t0 = m0 & 2047;
#pragma unroll
        for (int i = 0; i < 4; i++) {
            const floatx4 gr = *(const floatx4*)&gT[hh2 * 128 + wm + i * 16 + quad * 4];
            const int tslot = t0 + wm + (i >> 1) * 32 + quad * 8 + (i & 1) * 4;
#pragma unroll
            for (int j = 0; j < 4; j++) {
                bf16x4 o;
#pragma unroll
                for (int r = 0; r < 4; r++) {
                    const float vef = (float)veT[(wm + i * 16 + quad * 4 + r) * 136
                                                 + wn + j * 16 + m16];
                    o[r] = (bf16_t)(acc[i][j][r] + gr[r] * vef);
                }
                *(bf16x4*)&vt[((size_t)(bb * NH_ + head) * HD_ + j * 16 + m16) * T_
                              + tslot] = o;
            }
        }
    }
}

// ---------------------------------------------------------------------------
// Plain GEMM for the output projection (round-4-proven).
// ---------------------------------------------------------------------------
template <bool OUT_BF16>
__device__ __forceinline__ void gemm_bt_tile(
    const bf16_t* __restrict__ A, const bf16_t* __restrict__ Bm,
    void* __restrict__ Cout, int m0, int n0, int K, int ldc)
{
    __shared__ bf16_t As[2][128 * 32];
    __shared__ bf16_t Bs[2][128 * 32];
    const int tid  = threadIdx.x;
    const int lane = tid & 63;
    const int wid  = tid >> 6;
    const int m16  = lane & 15;
    const int quad = lane >> 4;
    const int wm   = (wid >> 1) * 64;
    const int wn   = (wid & 1) * 64;
    const int srow = lane >> 2;
    const int soct = (lane & 3) * 8;

    floatx4 acc[4][4];
#pragma unroll
    for (int i = 0; i < 4; i++)
#pragma unroll
        for (int j = 0; j < 4; j++) acc[i][j] = (floatx4){0.f, 0.f, 0.f, 0.f};

    for (int k0 = 0; k0 < K; k0 += 64) {
        const bf16_t* ga0 = &A[(size_t)(m0 + 16 * wid + srow) * K + k0 + soct];
        const bf16_t* gb0 = &Bm[(size_t)(n0 + 16 * wid + srow) * K + k0 + soct];
        gld16(ga0,                       (bf16_t*)As[0] + wid * 512);
        gld16(ga0 + (size_t)64 * K,      (bf16_t*)As[0] + wid * 512 + 2048);
        gld16(gb0,                       (bf16_t*)Bs[0] + wid * 512);
        gld16(gb0 + (size_t)64 * K,      (bf16_t*)Bs[0] + wid * 512 + 2048);
        gld16(ga0 + 32,                  (bf16_t*)As[1] + wid * 512);
        gld16(ga0 + (size_t)64 * K + 32, (bf16_t*)As[1] + wid * 512 + 2048);
        gld16(gb0 + 32,                  (bf16_t*)Bs[1] + wid * 512);
        gld16(gb0 + (size_t)64 * K + 32, (bf16_t*)Bs[1] + wid * 512 + 2048);
        __syncthreads();
#pragma unroll
        for (int half = 0; half < 2; half++) {
            bf16x8 af[4], bfr[4];
#pragma unroll
            for (int i = 0; i < 4; i++)
                af[i] = *(const bf16x8*)&As[half][(wm + i * 16 + m16) * 32 + quad * 8];
#pragma unroll
            for (int j = 0; j < 4; j++)
                bfr[j] = *(const bf16x8*)&Bs[half][(wn + j * 16 + m16) * 32 + quad * 8];
#pragma unroll
            for (int i = 0; i < 4; i++)
#pragma unroll
                for (int j = 0; j < 4; j++)
                    acc[i][j] = MFMA16(af[i], bfr[j], acc[i][j]);
        }
        __syncthreads();
    }
#pragma unroll
    for (int i = 0; i < 4; i++) {
#pragma unroll
        for (int j = 0; j < 4; j++) {
            const int colg = n0 + wn + j * 16 + m16;
#pragma unroll
            for (int r = 0; r < 4; r++) {
                const int rowg = m0 + wm + i * 16 + quad * 4 + r;
                if (OUT_BF16)
                    ((bf16_t*)Cout)[(size_t)rowg * ldc + colg] = (bf16_t)acc[i][j][r];
                else
                    ((float*)Cout)[(size_t)rowg * ldc + colg] = acc[i][j][r];
            }
        }
    }
}

__global__ __launch_bounds__(256, 3) void gemm_proj_kernel(
    const bf16_t* __restrict__ yb, const void* wpr, const bf16_t* wpc,
    void* __restrict__ out, const void* cr)
{
    const bool f32 = (((const unsigned short*)cr)[0] == 0);
    const bf16_t* WP = f32 ? wpc : (const bf16_t*)wpr;
    if (f32)
        gemm_bt_tile<false>(yb, WP, out, blockIdx.x * 128, blockIdx.y * 128, C_, C_);
    else
        gemm_bt_tile<true>(yb, WP, out, blockIdx.x * 128, blockIdx.y * 128, C_, C_);
}

// ---------------------------------------------------------------------------
// Flash attention (round-4-proven kernel; Q/K row stride C_).
// ---------------------------------------------------------------------------
__global__ __launch_bounds__(256, 3) void attn_kernel(
    const bf16_t* __restrict__ Q, const bf16_t* __restrict__ Km,
    const bf16_t* __restrict__ Vtg, bf16_t* __restrict__ Y,
    const int* __restrict__ wl)
{
    const int bx   = blockIdx.x;
    const int bh   = blockIdx.y;
    const int gsel = bh >> 4;
    int qblk;
    if (gsel == 0)      qblk = bx;
    else if (gsel == 1) qblk = 15 - bx;
    else                qblk = (int)((0xECA8642013579BDFull >> (bx * 4)) & 0xF);
    const int q0 = qblk * 128;
    const int b  = bh / NH_;
    const int h  = bh % NH_;
    const int window = wl[0];
    const int tid  = threadIdx.x;
    const int wid  = tid >> 6;
    const int lane = tid & 63;
    const int m16  = lane & 15;
    const int quad = lane >> 4;
    const int qw   = q0 + wid * 32;

    const bf16_t* Qb = Q + (size_t)b * T_ * C_ + h * HD_;   // row stride C_
    const bf16_t* Kb = Km + (size_t)b * T_ * C_ + h * HD_;
    const bf16_t* Vb = Vtg + (size_t)bh * HD_ * T_;         // [d][t-perm]

    __shared__ bf16_t Ks[2][64 * 64];
    __shared__ bf16_t Vs[2][64 * 64];

    bf16x8 qf[2][2];
#pragma unroll
    for (int mt = 0; mt < 2; mt++)
#pragma unroll
        for (int ks = 0; ks < 2; ks++)
            qf[mt][ks] = *(const bf16x8*)
                &Qb[(size_t)(qw + mt * 16 + m16) * C_ + ks * 32 + quad * 8];

    // staging: thread -> (row = tid>>2, two octets), XOR-swizzled columns
    const int srow = tid >> 2;
    const int soct = tid & 3;
    const int g0   = 2 * soct, g1 = 2 * soct + 1;
    const int kd0  = srow * 64 + ((g0 ^ (srow & 7)) << 3);
    const int kd1  = srow * 64 + ((g1 ^ (srow & 7)) << 3);
    int rsw[2];
#pragma unroll
    for (int ks = 0; ks < 2; ks++)
        rsw[ks] = (((ks * 4 + quad) ^ (m16 & 7)) << 3);

    int lo = q0 - window;
    if (lo < 0) lo = 0;
    lo &= ~63;
    const int nch = (q0 + 128 - lo) >> 6;

    floatx4 accO[2][4];
#pragma unroll
    for (int mt = 0; mt < 2; mt++)
#pragma unroll
        for (int dt = 0; dt < 4; dt++) accO[mt][dt] = (floatx4){0.f, 0.f, 0.f, 0.f};
    float lsum[2] = {0.f, 0.f};
    const bf16x4 zero4 = {(bf16_t)0.f, (bf16_t)0.f, (bf16_t)0.f, (bf16_t)0.f};

    // preload + stage chunk 0
    bf16x8 ka0 = *(const bf16x8*)&Kb[(size_t)(lo + srow) * C_ + g0 * 8];
    bf16x8 ka1 = *(const bf16x8*)&Kb[(size_t)(lo + srow) * C_ + g1 * 8];
    bf16x8 va0 = *(const bf16x8*)&Vb[(size_t)srow * T_ + lo + g0 * 8];
    bf16x8 va1 = *(const bf16x8*)&Vb[(size_t)srow * T_ + lo + g1 * 8];
    *(bf16x8*)&Ks[0][kd0] = ka0;
    *(bf16x8*)&Ks[0][kd1] = ka1;
    *(bf16x8*)&Vs[0][kd0] = va0;
    *(bf16x8*)&Vs[0][kd1] = va1;

    for (int ic = 0; ic < nch; ic++) {
        const int kc = lo + ic * 64;
        const bool more = (ic + 1 < nch);
        if (more) {
            const int kn2 = kc + 64;
            ka0 = *(const bf16x8*)&Kb[(size_t)(kn2 + srow) * C_ + g0 * 8];
            ka1 = *(const bf16x8*)&Kb[(size_t)(kn2 + srow) * C_ + g1 * 8];
            va0 = *(const bf16x8*)&Vb[(size_t)srow * T_ + kn2 + g0 * 8];
            va1 = *(const bf16x8*)&Vb[(size_t)srow * T_ + kn2 + g1 * 8];
        }
        __syncthreads();
        const int buf = ic & 1;

        const bool skip = (kc > qw + 31) || (kc + 63 < qw - window);
        if (!skip) {
            bf16x8 kf[4][2];
#pragma unroll
            for (int nt = 0; nt < 4; nt++) {
                const int rb = (nt * 16 + m16) * 64;
                kf[nt][0] = *(const bf16x8*)&Ks[buf][rb + rsw[0]];
                kf[nt][1] = *(const bf16x8*)&Ks[buf][rb + rsw[1]];
            }
            bf16x4 pk[2][4];
            unsigned livemask = 0;
#pragma unroll
            for (int mt = 0; mt < 2; mt++) {
                const int qmin = qw + mt * 16, qmax = qmin + 15;
                float lacc = 0.f;
#pragma unroll
                for (int nt = 0; nt < 4; nt++) {
                    const int kmin = kc + nt * 16, kmax = kmin + 15;
                    if (kmin > qmax || kmax < qmin - window) {
                        pk[mt][nt] = zero4;
                        continue;
                    }
                    livemask |= 1u << (mt * 4 + nt);
                    floatx4 z = (floatx4){0.f, 0.f, 0.f, 0.f};
                    z = MFMA16(kf[nt][0], qf[mt][0], z);
                    z = MFMA16(kf[nt][1], qf[mt][1], z);
                    const bool edge = (kmax > qmin) || (kmin < qmax - window);
                    const int query = qmin + m16;
                    bf16x4 t4;
#pragma unroll
                    for (int r = 0; r < 4; r++) {
                        float p = __builtin_amdgcn_exp2f(
                            fmaf(z[r], SM_C1, SM_C2));
                        if (edge) {
                            const int key = kmin + quad * 4 + r;
                            const bool ok = (key <= query) &&
                                            (query - key <= window);
                            p = ok ? p : 0.f;
                        }
                        t4[r] = (bf16_t)p;
                        lacc += p;
                    }
                    pk[mt][nt] = t4;
                }
                lsum[mt] += lacc;
            }
#pragma unroll
            for (int pr = 0; pr < 2; pr++) {
                const unsigned pm0 = (livemask >> (2 * pr)) & 3u;
                const unsigned pm1 = (livemask >> (4 + 2 * pr)) & 3u;
                if (!(pm0 | pm1)) continue;
                const bf16x8 pa0 = __builtin_shufflevector(
                    pk[0][2 * pr], pk[0][2 * pr + 1], 0, 1, 2, 3, 4, 5, 6, 7);
                const bf16x8 pa1 = __builtin_shufflevector(
                    pk[1][2 * pr], pk[1][2 * pr + 1], 0, 1, 2, 3, 4, 5, 6, 7);
                const int vco = (((pr * 4 + quad) ^ (m16 & 7)) << 3);
#pragma unroll
                for (int dt = 0; dt < 4; dt++) {
                    const bf16x8 vf = *(const bf16x8*)
                        &Vs[buf][(dt * 16 + m16) * 64 + vco];
                    if (pm0) accO[0][dt] = MFMA16(pa0, vf, accO[0][dt]);
                    if (pm1) accO[1][dt] = MFMA16(pa1, vf, accO[1][dt]);
                }
            }
        }

        if (more) {
            const int nb = buf ^ 1;
            *(bf16x8*)&Ks[nb][kd0] = ka0;
            *(bf16x8*)&Ks[nb][kd1] = ka1;
            *(bf16x8*)&Vs[nb][kd0] = va0;
            *(bf16x8*)&Vs[nb][kd1] = va1;
        }
    }

#pragma unroll
    for (int mt = 0; mt < 2; mt++) {
        float red = lsum[mt];
        red += __shfl_xor(red, 16, 64);
        red += __shfl_xor(red, 32, 64);
#pragma unroll
        for (int r = 0; r < 4; r++) {
            const float lq  = __shfl(red, quad * 4 + r, 64);
            const float inv = 1.f / lq;
            const int   tq  = qw + mt * 16 + quad * 4 + r;
#pragma unroll
            for (int dt = 0; dt < 4; dt++)
                Y[((size_t)b * T_ + tq) * C_ + h * HD_ + dt * 16 + m16] =
                    (bf16_t)(accO[mt][dt][r] * inv);
        }
    }
}

// ---------------------------------------------------------------------------
extern "C" void kernel_launch(void* const* d_in, const int* in_sizes, int n_in,
                              void* d_out, int out_size, void* d_ws, size_t ws_size,
                              hipStream_t stream)
{
    const void* x_raw   = d_in[0];
    const void* ve_raw  = d_in[1];
    const void* cos_raw = d_in[2];
    const void* sin_raw = d_in[3];
    const void* wq_raw  = d_in[4];
    const void* wk_raw  = d_in[5];
    const void* wv_raw  = d_in[6];
    const void* wp_raw  = d_in[7];
    const void* wg_raw  = d_in[8];
    const int*  wl      = (const int*)d_in[9];

    const size_t NTC = (size_t)B_ * T_ * C_;  // 6291456
    const size_t WSZ = (size_t)C_ * C_;       // 589824

    bf16_t* ws  = (bf16_t*)d_ws;
    bf16_t* xb  = ws;                 // NTC   (fp32-cvt targets)
    bf16_t* veb = xb + NTC;           // NTC
    bf16_t* cb  = veb + NTC;          // 65536
    bf16_t* sb  = cb + T_ * 32;       // 65536
    bf16_t* wqb = sb + T_ * 32;       // WSZ x4
    bf16_t* wkb = wqb + WSZ;
    bf16_t* wvb = wkb + WSZ;
    bf16_t* wpb = wvb + WSZ;
    bf16_t* wgb = wpb + WSZ;          // 144 (pad 256)
    bf16_t* qn  = wgb + 256;          // NTC  rope+rms Q  [b][t][C]
    bf16_t* kn  = qn + NTC;           // NTC  rope+rms K  [b][t][C]
    bf16_t* vt  = kn + NTC;           // NTC  V^T [bh][d][t-perm]
    bf16_t* yb  = vt + NTC;           // NTC  attention out [b][t][C]

    cvt_all_kernel<<<dim3(128, 9), 256, 0, stream>>>(
        x_raw, ve_raw, cos_raw, sin_raw, wq_raw, wk_raw, wv_raw, wp_raw, wg_raw,
        xb, veb, cb, sb, wqb, wkb, wvb, wpb, wgb);

    gemm_qkv_fused<<<dim3(64, 18), 256, 0, stream>>>(
        x_raw, xb, wq_raw, wqb, wk_raw, wkb, wv_raw, wvb,
        cos_raw, cb, sin_raw, sb, ve_raw, veb, wg_raw, wgb,
        qn, kn, vt);

    attn_kernel<<<dim3(16, 48), 256, 0, stream>>>(qn, kn, vt, yb, wl);

    gemm_proj_kernel<<<dim3(64, 6), 256, 0, stream>>>(yb, wp_raw, wpb, d_out, cos_raw);
}